// Round 11
// baseline (444.024 us; speedup 1.0000x reference)
//
#include <hip/hip_runtime.h>
#include <cstdint>
#include <cstddef>

#define HD   1024
#define SEQL 200
#define MEMN 50
#define RTOT 51200   // 256 * 200
#define KP   128
#define PADK 136     // KP + 8 bf16 pad -> LDS row stride 272B (2-way, free)

typedef float  f4    __attribute__((ext_vector_type(4)));
typedef float  f32x4 __attribute__((ext_vector_type(4)));
typedef short  s16x8 __attribute__((ext_vector_type(8)));
typedef unsigned short u16;
typedef unsigned short u16x4 __attribute__((ext_vector_type(4)));
typedef unsigned short u16x8 __attribute__((ext_vector_type(8)));

__device__ __forceinline__ u16 f2bf(float f) {
    unsigned u = __builtin_bit_cast(unsigned, f);
    u += 0x7FFFu + ((u >> 16) & 1u);          // RNE
    return (u16)(u >> 16);
}
__device__ __forceinline__ float bf2f(u16 h) {
    unsigned u = ((unsigned)h) << 16;
    return __builtin_bit_cast(float, u);
}

#define GLOAD_LDS16(g, l) __builtin_amdgcn_global_load_lds( \
    (const __attribute__((address_space(1))) unsigned int*)(g), \
    (__attribute__((address_space(3))) unsigned int*)(l), 16, 0, 0)

#define WAITV6 asm volatile("s_waitcnt vmcnt(6)" ::: "memory")
#define WAITV0 asm volatile("s_waitcnt vmcnt(0)" ::: "memory")
#define LGKMFENCE asm volatile("s_waitcnt lgkmcnt(0)" ::: "memory")
#define SCHB   __builtin_amdgcn_sched_barrier(0)

// ---------------------------------------------------------------------------
// K0a: gate_w f32 -> bf16, layout [o][2048] k-contig. Wf = cols 0..1023,
//      Wm = cols 1024..2047.
// ---------------------------------------------------------------------------
__global__ __launch_bounds__(256) void k_cvt_w(const float* __restrict__ gw,
                                               u16* __restrict__ gwB)
{
    const size_t i = ((size_t)blockIdx.x * 256 + threadIdx.x) * 8;
    f4 v0 = *(const f4*)&gw[i];
    f4 v1 = *(const f4*)&gw[i + 4];
    u16x4 b0 = { f2bf(v0.x), f2bf(v0.y), f2bf(v0.z), f2bf(v0.w) };
    u16x4 b1 = { f2bf(v1.x), f2bf(v1.y), f2bf(v1.z), f2bf(v1.w) };
    *(u16x4*)&gwB[i]     = b0;
    *(u16x4*)&gwB[i + 4] = b1;
}

// ---------------------------------------------------------------------------
// K0b: spatial memory -> {memHi, memLo} [64][1024] bf16 (rows 50..63 zero)
//      and memT [1024][64] bf16 (hi, transposed, zero-padded).
// ---------------------------------------------------------------------------
__global__ __launch_bounds__(256) void k_prep_mem(const float* __restrict__ sm,
                                                  u16* __restrict__ memHi,
                                                  u16* __restrict__ memLo,
                                                  u16* __restrict__ memT)
{
    const int idx = blockIdx.x * 256 + threadIdx.x;   // 16384 total
    const int m  = idx >> 8;
    const int h0 = (idx & 255) * 4;
    f4 v = {0.f, 0.f, 0.f, 0.f};
    if (m < MEMN) v = *(const f4*)&sm[(size_t)m * HD + h0];
    u16x4 hi = { f2bf(v.x), f2bf(v.y), f2bf(v.z), f2bf(v.w) };
    f4 hv = { bf2f(hi.x), bf2f(hi.y), bf2f(hi.z), bf2f(hi.w) };
    f4 lv = v - hv;
    u16x4 lo = { f2bf(lv.x), f2bf(lv.y), f2bf(lv.z), f2bf(lv.w) };
    *(u16x4*)&memHi[(size_t)m * HD + h0] = hi;
    *(u16x4*)&memLo[(size_t)m * HD + h0] = lo;
    memT[(size_t)(h0 + 0) * 64 + m] = hi.x;
    memT[(size_t)(h0 + 1) * 64 + m] = hi.y;
    memT[(size_t)(h0 + 2) * 64 + m] = hi.z;
    memT[(size_t)(h0 + 3) * 64 + m] = hi.w;
}

// ---------------------------------------------------------------------------
// K0d: MWmT[o][m] = (M @ Wm)(m,o) as bf16, [1024][64].  MFMA, 16 blocks.
// ---------------------------------------------------------------------------
__global__ __launch_bounds__(256) void k_mwm(const u16* __restrict__ memHi,
                                             const u16* __restrict__ gwB,
                                             u16* __restrict__ MWmT)
{
    const int tid = threadIdx.x, lane = tid & 63, w = tid >> 6;
    const int fr = lane & 15, fk = (lane >> 4) * 8, jr = (lane >> 4) * 4;
    const int ob = blockIdx.x * 64 + w * 16;       // o-base of this wave
    f32x4 acc[4] = {};
    for (int ks = 0; ks < 32; ++ks) {
        s16x8 b = *(const s16x8*)&gwB[(size_t)(ob + fr) * 2048 + 1024 + ks * 32 + fk];
        #pragma unroll
        for (int mt = 0; mt < 4; ++mt) {
            s16x8 a = *(const s16x8*)&memHi[(size_t)(mt * 16 + fr) * HD + ks * 32 + fk];
            acc[mt] = __builtin_amdgcn_mfma_f32_16x16x32_bf16(a, b, acc[mt], 0, 0, 0);
        }
    }
    #pragma unroll
    for (int mt = 0; mt < 4; ++mt)
        #pragma unroll
        for (int j = 0; j < 4; ++j)
            MWmT[(size_t)(ob + fr) * 64 + mt * 16 + jr + j] = f2bf(acc[mt][j]);
}

// ---------------------------------------------------------------------------
// K1: feats = x + pos (f32); featsB = bf16(feats) = hi; lo = bf16(feats-hi);
//     sim = feats(hi/lo) @ M(hi/lo)^T, 3 split-pass MFMA (lo*lo dropped);
//     softmax -> wBg [51200][64] bf16 (zero-padded). Barrier-free;
//     register-prefetch of next panel; 16B stores.
// ---------------------------------------------------------------------------
__global__ __launch_bounds__(256) void k_pre(
    const float* __restrict__ x, const float* __restrict__ pos,
    const u16* __restrict__ memHi, const u16* __restrict__ memLo,
    u16* __restrict__ featsB, u16* __restrict__ wBg)
{
    __shared__ u16 fHi[64 * PADK];
    __shared__ u16 fLo[64 * PADK];

    const int tid  = threadIdx.x;
    const int r0   = blockIdx.x * 64;
    const int lane = tid & 63, w = tid >> 6;
    const int fr   = lane & 15;
    const int fk   = (lane >> 4) * 8;
    const int jr   = (lane >> 4) * 4;

    const int srow = tid >> 2;            // 16w..16w+15: wave's own rows
    const int scol = (tid & 3) * 8;       // 8 contiguous cols -> 16B stores
    const int prow = (r0 + srow) % SEQL;

    const float* xrow = &x[(size_t)(r0 + srow) * HD];
    const float* prp  = &pos[(size_t)prow * HD];

    f4 xa[4][2], pa[4][2];
    #pragma unroll
    for (int i = 0; i < 4; ++i) {
        const int c = scol + i * 32;
        xa[i][0] = *(const f4*)&xrow[c];
        xa[i][1] = *(const f4*)&xrow[c + 4];
        pa[i][0] = *(const f4*)&prp[c];
        pa[i][1] = *(const f4*)&prp[c + 4];
    }

    f32x4 acc[4] = {};                    // sim[16 rows][m = n*16 + fr]

    for (int kp = 0; kp < HD; kp += KP) {
        // ---- convert current panel regs -> LDS hi/lo + featsB (16B) ----
        #pragma unroll
        for (int i = 0; i < 4; ++i) {
            const int c = scol + i * 32;
            f4 fa = xa[i][0] + pa[i][0];
            f4 fb = xa[i][1] + pa[i][1];
            u16x8 hi = { f2bf(fa.x), f2bf(fa.y), f2bf(fa.z), f2bf(fa.w),
                         f2bf(fb.x), f2bf(fb.y), f2bf(fb.z), f2bf(fb.w) };
            *(u16x8*)&featsB[(size_t)(r0 + srow) * HD + kp + c] = hi;
            f4 hv0 = { bf2f(hi[0]), bf2f(hi[1]), bf2f(hi[2]), bf2f(hi[3]) };
            f4 hv1 = { bf2f(hi[4]), bf2f(hi[5]), bf2f(hi[6]), bf2f(hi[7]) };
            f4 l0 = fa - hv0, l1 = fb - hv1;
            u16x8 lo = { f2bf(l0.x), f2bf(l0.y), f2bf(l0.z), f2bf(l0.w),
                         f2bf(l1.x), f2bf(l1.y), f2bf(l1.z), f2bf(l1.w) };
            *(u16x8*)&fHi[srow * PADK + c] = hi;
            *(u16x8*)&fLo[srow * PADK + c] = lo;
        }
        LGKMFENCE;   // wave-local: LDS writes visible to this wave's reads

        // ---- prefetch next panel into regs (hides HBM under MFMA below) ----
        if (kp + KP < HD) {
            #pragma unroll
            for (int i = 0; i < 4; ++i) {
                const int c = kp + KP + scol + i * 32;
                xa[i][0] = *(const f4*)&xrow[c];
                xa[i][1] = *(const f4*)&xrow[c + 4];
                pa[i][0] = *(const f4*)&prp[c];
                pa[i][1] = *(const f4*)&prp[c + 4];
            }
        }

        // ---- sim MFMA: 3 split-passes, B-frags from L2 (256KB resident) ----
        #pragma unroll
        for (int ks = 0; ks < KP / 32; ++ks) {
            const int kb = ks * 32 + fk;
            s16x8 aH = *(const s16x8*)&fHi[(16 * w + fr) * PADK + kb];
            s16x8 aL = *(const s16x8*)&fLo[(16 * w + fr) * PADK + kb];
            #pragma unroll
            for (int n = 0; n < 4; ++n) {
                const size_t mb = (size_t)(n * 16 + fr) * HD + kp + kb;
                s16x8 bH = *(const s16x8*)&memHi[mb];
                s16x8 bL = *(const s16x8*)&memLo[mb];
                acc[n] = __builtin_amdgcn_mfma_f32_16x16x32_bf16(aH, bH, acc[n], 0, 0, 0);
                acc[n] = __builtin_amdgcn_mfma_f32_16x16x32_bf16(aH, bL, acc[n], 0, 0, 0);
                acc[n] = __builtin_amdgcn_mfma_f32_16x16x32_bf16(aL, bH, acc[n], 0, 0, 0);
            }
        }
        LGKMFENCE;   // panel reads done before next panel's writes
    }

    // softmax over m (50)
    #pragma unroll
    for (int j = 0; j < 4; ++j) {
        const int rg = r0 + 16 * w + jr + j;
        float v[4];
        float mx = -1e30f;
        #pragma unroll
        for (int n = 0; n < 4; ++n) {
            v[n] = acc[n][j];
            const int m = n * 16 + fr;
            if (m < MEMN) mx = fmaxf(mx, v[n]);
        }
        #pragma unroll
        for (int d = 1; d < 16; d <<= 1) mx = fmaxf(mx, __shfl_xor(mx, d));
        float e[4], s = 0.f;
        #pragma unroll
        for (int n = 0; n < 4; ++n) {
            const int m = n * 16 + fr;
            e[n] = (m < MEMN) ? __expf(v[n] - mx) : 0.f;
            s += e[n];
        }
        #pragma unroll
        for (int d = 1; d < 16; d <<= 1) s += __shfl_xor(s, d);
        const float inv = 1.f / s;
        #pragma unroll
        for (int n = 0; n < 4; ++n)
            wBg[(size_t)rg * 64 + n * 16 + fr] = f2bf(e[n] * inv); // 0 pad m>=50
    }
}

// ---------------------------------------------------------------------------
// K2: out = featsB + sigmoid([featsB|w]@[Wf;MWm] + b) * (w@M).
//     m201-style 8-phase port. BM=256, BN=128, BK=64, 8 waves (4Mx2N).
//     17 K-tiles (16 featsB@Wf + 1 w@MWm). 3 LDS buffers (144 KB), prefetch
//     distance 2, 2 phases/tile: {8 swizzled ds_read || 3 gload_lds ->
//     [phase B: vmcnt(6), publishes tile T+1 via barrier] -> barrier ->
//     lgkm0 -> setprio+16 MFMA -> barrier}. vmcnt never 0 mid-loop.
//     T2 both-sides XOR swizzle: pre-swizzled global source + same
//     involution on ds_read (r&7 == fr&7 on both sides).
// ---------------------------------------------------------------------------
__global__ __launch_bounds__(512, 2) void k_gate_out(
    const u16* __restrict__ featsB, const u16* __restrict__ wBg,
    const u16* __restrict__ gwB, const u16* __restrict__ memT,
    const u16* __restrict__ MWmT, const float* __restrict__ gb,
    float* __restrict__ out)
{
    __shared__ u16 As[3][256 * 64];   // 3 x 32 KB
    __shared__ u16 Bs[3][128 * 64];   // 3 x 16 KB

    const int tid = threadIdx.x;
    int bid = blockIdx.x;
    bid = (bid & 7) * 200 + (bid >> 3);      // XCD swizzle (1600 % 8 == 0)
    const int mt = bid >> 3, nt = bid & 7;   // 200 x 8 tiles
    const int row0 = mt * 256, col0 = nt * 128;
    const int lane = tid & 63, wave = tid >> 6;
    const int wm = wave >> 1, wn = wave & 1; // 4M x 2N (64x64 each)
    const int fr = lane & 15, sg = lane >> 4;
    const int fk = sg * 8;

    f32x4 acc[4][4] = {};

    // staging geometry: per gload, 512 lanes cover 64 rows x 8 slots of 16B
    const int rr = tid >> 3;                 // row within 64-row chunk
    const int sl = tid & 7;                  // LDS 16B slot
    // global source slot is pre-swizzled: srcSlot = sl ^ (row & 7)

    // stage chunk c (0/1) of K-tile kt into buffer buf: 3 gloads
    auto stageChunk = [&](int buf, int kt, int c) {
        if (kt < 16) {
            const int k0 = kt * 64;
            const int ra0 = c * 128 + rr;
            GLOAD_LDS16(featsB + (size_t)(row0 + ra0) * HD + k0 + ((sl ^ (ra0 & 7)) * 8),
                        &As[buf][(c * 128) * 64 + tid * 8]);
            const int ra1 = c * 128 + 64 + rr;
            GLOAD_LDS16(featsB + (size_t)(row0 + ra1) * HD + k0 + ((sl ^ (ra1 & 7)) * 8),
                        &As[buf][(c * 128 + 64) * 64 + tid * 8]);
            const int rb = c * 64 + rr;
            GLOAD_LDS16(gwB + (size_t)(col0 + rb) * 2048 + k0 + ((sl ^ (rb & 7)) * 8),
                        &Bs[buf][(c * 64) * 64 + tid * 8]);
        } else {                             // kt == 16: rank-64 tail
            const int ra0 = c * 128 + rr;
            GLOAD_LDS16(wBg + (size_t)(row0 + ra0) * 64 + ((sl ^ (ra0 & 7)) * 8),
                        &As[buf][(c * 128) * 64 + tid * 8]);
            const int ra1 = c * 128 + 64 + rr;
            GLOAD_LDS16(wBg + (size_t)(row0 + ra1) * 64 + ((sl ^ (ra1 & 7)) * 8),
                        &As[buf][(c * 128 + 64) * 64 + tid * 8]);
            const int rb = c * 64 + rr;
            GLOAD_LDS16(MWmT + (size_t)(col0 + rb) * 64 + ((sl ^ (rb & 7)) * 8),
                        &Bs[buf][(c * 64) * 64 + tid * 8]);
        }
    };

    // prologue: tiles 0 and 1 fully staged (12 loads in flight)
    stageChunk(0, 0, 0); stageChunk(0, 0, 1);
    stageChunk(1, 1, 0); stageChunk(1, 1, 1);
    WAITV6;                                  // tile 0 retired (mine)
    __builtin_amdgcn_s_barrier();            // publish across waves

    s16x8 aF[4], bF[4];

    for (int T = 0; T < 17; ++T) {
        const int buf = T % 3;
        const int nbuf = (T + 2) % 3;
        const bool doStage = (T + 2 <= 16);

        #pragma unroll
        for (int ph = 0; ph < 2; ++ph) {     // phase = K-half ks
            // ---- ds_read this phase's fragments (swizzled) ----
            #pragma unroll
            for (int i = 0; i < 4; ++i) {
                const int r = wm * 64 + i * 16 + fr;
                const int s = (ph * 4 + sg) ^ (fr & 7);
                aF[i] = *(const s16x8*)&As[buf][r * 64 + s * 8];
            }
            #pragma unroll
            for (int n = 0; n < 4; ++n) {
                const int r = wn * 64 + n * 16 + fr;
                const int s = (ph * 4 + sg) ^ (fr & 7);
                bF[n] = *(const s16x8*)&Bs[buf][r * 64 + s * 8];
            }
            // ---- issue staging for tile T+2 (one chunk per phase) ----
            if (doStage) stageChunk(nbuf, T + 2, ph);
            // ---- phase B: counted wait publishing tile T+1 ----
            if (ph == 1) {
                if (T <= 14)      WAITV6;    // leaves exactly tile T+2's 6
                else if (T == 15) WAITV0;    // drain tile 16 (tail only)
            }
            __builtin_amdgcn_s_barrier();
            LGKMFENCE;                        // my ds_reads complete
            SCHB;                             // rule 18: pin MFMA after fence
            __builtin_amdgcn_s_setprio(1);
            #pragma unroll
            for (int i = 0; i < 4; ++i)
                #pragma unroll
                for (int n = 0; n < 4; ++n)
                    acc[i][n] = __builtin_amdgcn_mfma_f32_16x16x32_bf16(
                        aF[i], bF[n], acc[i][n], 0, 0, 0);
            __builtin_amdgcn_s_setprio(0);
            __builtin_amdgcn_s_barrier();
        }
    }

    // epilogue: accR = w@M per (m,n); out = feats + sigmoid(acc+b)*accR
    #pragma unroll
    for (int m = 0; m < 4; ++m) {
        const size_t ab = (size_t)(row0 + wm * 64 + m * 16 + fr) * 64 + fk;
        s16x8 a2_0 = *(const s16x8*)&wBg[ab];
        s16x8 a2_1 = *(const s16x8*)&wBg[ab + 32];
        #pragma unroll
        for (int n = 0; n < 4; ++n) {
            const size_t cb = (size_t)(col0 + wn * 64 + n * 16 + fr) * 64 + fk;
            s16x8 bT0 = *(const s16x8*)&memT[cb];
            s16x8 bT1 = *(const s16x8*)&memT[cb + 32];
            f32x4 accR = {};
            accR = __builtin_amdgcn_mfma_f32_16x16x32_bf16(a2_0, bT0, accR, 0, 0, 0);
            accR = __builtin_amdgcn_mfma_f32_16x16x32_bf16(a2_1, bT1, accR, 0, 0, 0);

            const int crow = row0 + wm * 64 + m * 16 + sg * 4;
            const int ccol = col0 + wn * 64 + n * 16 + fr;
            const float bias = gb[ccol];
            #pragma unroll
            for (int j = 0; j < 4; ++j) {
                const size_t idx = (size_t)(crow + j) * HD + ccol;
                const float fe = bf2f(featsB[idx]);
                const float pre = acc[m][n][j] + bias;
                const float g = 1.0f / (1.0f + __expf(-pre));
                out[idx] = fe + g * accR[j];
            }
        }
    }
}

// ---------------------------------------------------------------------------
extern "C" void kernel_launch(void* const* d_in, const int* in_sizes, int n_in,
                              void* d_out, int out_size, void* d_ws, size_t ws_size,
                              hipStream_t stream)
{
    const float* x   = (const float*)d_in[0];
    const float* sm  = (const float*)d_in[1];
    const float* pos = (const float*)d_in[2];
    const float* gw  = (const float*)d_in[3];
    const float* gb  = (const float*)d_in[4];
    float* out = (float*)d_out;

    u16* featsB = (u16*)d_ws;                          // 51200*1024
    u16* gwB    = featsB + (size_t)RTOT * HD;          // 1024*2048
    u16* wBg    = gwB + (size_t)HD * 2048;             // 51200*64
    u16* memHi  = wBg + (size_t)RTOT * 64;             // 64*1024
    u16* memLo  = memHi + 64 * HD;                     // 64*1024
    u16* memT   = memLo + 64 * HD;                     // 1024*64
    u16* MWmT   = memT + (size_t)HD * 64;              // 1024*64

    k_cvt_w<<<dim3(1024), dim3(256), 0, stream>>>(gw, gwB);
    k_prep_mem<<<dim3(64), dim3(256), 0, stream>>>(sm, memHi, memLo, memT);
    k_mwm<<<dim3(16), dim3(256), 0, stream>>>(memHi, gwB, MWmT);
    k_pre<<<dim3(RTOT / 64), dim3(256), 0, stream>>>(x, pos, memHi, memLo,
                                                     featsB, wBg);
    k_gate_out<<<dim3(1600), dim3(512), 0, stream>>>(featsB, wBg, gwB, memT,
                                                     MWmT, gb, out);
}